// Round 6
// baseline (435.348 us; speedup 1.0000x reference)
//
#include <hip/hip_runtime.h>
#include <hip/hip_bf16.h>
#include <math.h>

typedef __hip_bfloat16 BF;
typedef __bf16 bf16x8 __attribute__((ext_vector_type(8)));
typedef float f32x4 __attribute__((ext_vector_type(4)));

struct alignas(8) BF4 { BF v[4]; };
struct alignas(16) BF8 { BF v[8]; };

static __device__ __forceinline__ float b2f(BF x) { return __bfloat162float(x); }
static __device__ __forceinline__ BF f2b(float x) { return __float2bfloat16(x); }

// async global->LDS, 16B per lane; LDS dest = wave-uniform base (+lane*16 implicit)
static __device__ __forceinline__ void gld_lds16(const void* g, void* l) {
  __builtin_amdgcn_global_load_lds(
      (const __attribute__((address_space(1))) unsigned int*)g,
      (__attribute__((address_space(3))) unsigned int*)l, 16, 0, 0);
}

// ---------------------------------------------------------------------------
// f32 -> bf16 convert, 4 elements/thread, grid-stride
// ---------------------------------------------------------------------------
__global__ void __launch_bounds__(256) cvt_kernel(
    const float* __restrict__ in, BF* __restrict__ out, int n4) {
  for (int i = blockIdx.x * 256 + threadIdx.x; i < n4; i += gridDim.x * 256) {
    float4 v = ((const float4*)in)[i];
    BF4 o;
    o.v[0] = f2b(v.x); o.v[1] = f2b(v.y); o.v[2] = f2b(v.z); o.v[3] = f2b(v.w);
    ((BF4*)out)[i] = o;
  }
}

// concat bk||bv -> bkv (f32), 2 blocks x 256
__global__ void __launch_bounds__(256) bkv_kernel(
    const float* __restrict__ bk, const float* __restrict__ bv,
    float* __restrict__ bkv) {
  int i = blockIdx.x * 256 + threadIdx.x;
  bkv[i] = (i < 256) ? bk[i] : bv[i - 256];
}

// ---------------------------------------------------------------------------
// rel-bias kernel: one thread per (window w, l=qi*4+kj). out[w*128+nh*16+l], f32
// ---------------------------------------------------------------------------
__global__ void __launch_bounds__(256) bias_kernel(
    const float* __restrict__ s_pos, const float* __restrict__ x_pos,
    const float* __restrict__ pw1, const float* __restrict__ pb1,
    const float* __restrict__ bn_g, const float* __restrict__ bn_b,
    const float* __restrict__ bn_m, const float* __restrict__ bn_v,
    const float* __restrict__ pw2, const float* __restrict__ pb2,
    float* __restrict__ out) {
  int gid = blockIdx.x * 256 + threadIdx.x;   // [0, 16384*16)
  int w = gid >> 4, l = gid & 15;
  int b = w >> 12, wi = w & 4095;
  int i = l >> 2, j = l & 3;
  int e0 = i, e1 = 4 + i;
  float sp0 = s_pos[(((size_t)b * 2 + (e0 & 1)) * 4096 + wi) * 4 + (e0 >> 1)];
  float sp1 = s_pos[(((size_t)b * 2 + (e1 & 1)) * 4096 + wi) * 4 + (e1 >> 1)];
  float xp0 = x_pos[((size_t)b * 16384 + j * 4096 + wi) * 2 + 0];
  float xp1 = x_pos[((size_t)b * 16384 + j * 4096 + wi) * 2 + 1];
  float r0 = sp0 - xp0, r1 = sp1 - xp1;
  float acc[8];
#pragma unroll
  for (int p = 0; p < 8; ++p) acc[p] = pb2[p];
#pragma unroll
  for (int o = 0; o < 16; ++o) {
    float t = pw1[o * 2 + 0] * r0 + pw1[o * 2 + 1] * r1 + pb1[o];
    float sc = bn_g[o] / sqrtf(bn_v[o] + 1e-5f);
    t = (t - bn_m[o]) * sc + bn_b[o];
    t = fmaxf(t, 0.0f);
#pragma unroll
    for (int p = 0; p < 8; ++p) acc[p] += pw2[p * 16 + o] * t;
  }
#pragma unroll
  for (int p = 0; p < 8; ++p) out[(size_t)w * 128 + p * 16 + l] = acc[p];
}

// ---------------------------------------------------------------------------
// TN bf16 MFMA GEMM, double-buffered LDS + COUNTED vmcnt pipeline (T3+T4):
// raw s_barrier (no vmcnt(0) drain) so next-tile loads stay in flight across
// the barrier. C = epi(A @ Bw^T + bias). 128x128 tile, BK=64, 4 waves 2x2,
// 16x16x32 MFMA, bijective XCD swizzle.
// ---------------------------------------------------------------------------
enum { EPI_NONE = 0, EPI_RES = 1, EPI_GELU = 2 };

template <int EPI, typename AT, typename RT, typename CT>
__global__ void __launch_bounds__(256, 2) gemm_tn(
    const AT* __restrict__ A, const BF* __restrict__ Bw,
    const float* __restrict__ bias, const RT* __restrict__ Res,
    CT* __restrict__ C, int M, int N, int K) {
  constexpr bool F32A = __is_same(AT, float);
  alignas(16) __shared__ BF As[2][8][128][8];
  alignas(16) __shared__ BF Bs[2][8][128][8];
  const int ntiles = N >> 7;
  const int cpx = gridDim.x >> 3;
  const int bid = blockIdx.x;
  const int swz = (bid & 7) * cpx + (bid >> 3);   // XCD-chunked, bijective
  const int mt = swz / ntiles, nt = swz % ntiles;
  const int row0 = mt << 7, col0 = nt << 7;
  const int t = threadIdx.x;
  const int wave = t >> 6, lane = t & 63;
  const int wr = wave >> 1, wc = wave & 1;
  const int sm = t & 127;      // staging row within tile
  const int skc = t >> 7;      // staging k-chunk parity
  f32x4 acc[4][4] = {};
  const int NT = K >> 6;
  float4 ar[4][2];

  auto stageB = [&](int kt, int d) {
#pragma unroll
    for (int i = 0; i < 4; ++i) {
      const int kc = i * 2 + skc;
      gld_lds16(Bw + (size_t)(col0 + sm) * K + kt * 64 + kc * 8,
                &Bs[d][0][0][0] + (size_t)(i * 256 + wave * 64) * 8);
    }
  };
  auto loadA = [&](int kt) {
    if constexpr (F32A) {
#pragma unroll
      for (int i = 0; i < 4; ++i) {
        const int kc = i * 2 + skc;
        const float* src = A + (size_t)(row0 + sm) * K + kt * 64 + kc * 8;
        ar[i][0] = ((const float4*)src)[0];
        ar[i][1] = ((const float4*)src)[1];
      }
    }
  };
  auto writeA = [&](int d) {
    if constexpr (F32A) {
#pragma unroll
      for (int i = 0; i < 4; ++i) {
        const int kc = i * 2 + skc;
        BF tmp[8];
        tmp[0] = f2b(ar[i][0].x); tmp[1] = f2b(ar[i][0].y);
        tmp[2] = f2b(ar[i][0].z); tmp[3] = f2b(ar[i][0].w);
        tmp[4] = f2b(ar[i][1].x); tmp[5] = f2b(ar[i][1].y);
        tmp[6] = f2b(ar[i][1].z); tmp[7] = f2b(ar[i][1].w);
        *(bf16x8*)(&As[d][kc][sm][0]) = *(bf16x8*)tmp;
      }
    }
  };
  auto stageA_bf = [&](int kt, int d) {
    if constexpr (!F32A) {
#pragma unroll
      for (int i = 0; i < 4; ++i) {
        const int kc = i * 2 + skc;
        gld_lds16((const BF*)A + (size_t)(row0 + sm) * K + kt * 64 + kc * 8,
                  &As[d][0][0][0] + (size_t)(i * 256 + wave * 64) * 8);
      }
    }
  };
  auto compute = [&](int d) {
#pragma unroll
    for (int kk = 0; kk < 2; ++kk) {
      const int chunk = kk * 4 + (lane >> 4);
      const int rl = lane & 15;
      bf16x8 af[4], bfr[4];
#pragma unroll
      for (int mi = 0; mi < 4; ++mi)
        af[mi] = *(const bf16x8*)(&As[d][chunk][wr * 64 + mi * 16 + rl][0]);
#pragma unroll
      for (int ni = 0; ni < 4; ++ni)
        bfr[ni] = *(const bf16x8*)(&Bs[d][chunk][wc * 64 + ni * 16 + rl][0]);
#pragma unroll
      for (int mi = 0; mi < 4; ++mi)
#pragma unroll
        for (int ni = 0; ni < 4; ++ni)
          acc[mi][ni] = __builtin_amdgcn_mfma_f32_16x16x32_bf16(
              af[mi], bfr[ni], acc[mi][ni], 0, 0, 0);
    }
  };

  // prologue: B(0) issued BEFORE A(0) so any wait covering A(0) implies B(0)
  if constexpr (F32A) {
    stageB(0, 0);
    loadA(0);
  } else {
    stageA_bf(0, 0);
    stageB(0, 0);
  }
  for (int kt = 0; kt < NT; ++kt) {
    const int cur = kt & 1, nxt = cur ^ 1;
    const bool more = kt + 1 < NT;
    if constexpr (F32A) {
      writeA(cur);   // compiler vmcnt-waits ar(kt); in-order => B(kt) also done
      if (more) {
        stageB(kt + 1, nxt);   // 4 gld_lds
        loadA(kt + 1);         // 8 global_load_dwordx4 (stay in flight)
        asm volatile("s_waitcnt vmcnt(12) lgkmcnt(0)" ::: "memory");
      } else {
        asm volatile("s_waitcnt vmcnt(0) lgkmcnt(0)" ::: "memory");
      }
    } else {
      if (more) {
        stageA_bf(kt + 1, nxt);  // 4 gld_lds
        stageB(kt + 1, nxt);     // 4 gld_lds -> 8 newer than tile kt's 8
        asm volatile("s_waitcnt vmcnt(8)" ::: "memory");
      } else {
        asm volatile("s_waitcnt vmcnt(0)" ::: "memory");
      }
    }
    __builtin_amdgcn_s_barrier();          // raw: no implicit vmcnt(0) drain
    __builtin_amdgcn_sched_barrier(0);     // pin: no LDS-read hoist above wait
    compute(cur);
    __builtin_amdgcn_s_barrier();          // all reads of cur done before reuse
  }

  // epilogue: D layout col = lane&15, row = (lane>>4)*4 + r (m89-verified)
  const int rl = lane & 15, rg = lane >> 4;
#pragma unroll
  for (int mi = 0; mi < 4; ++mi) {
#pragma unroll
    for (int ni = 0; ni < 4; ++ni) {
      const int col = col0 + wc * 64 + ni * 16 + rl;
      const float bcol = bias[col];
#pragma unroll
      for (int r = 0; r < 4; ++r) {
        const int row = row0 + wr * 64 + mi * 16 + rg * 4 + r;
        float v = acc[mi][ni][r] + bcol;
        if constexpr (EPI == EPI_GELU)
          v = 0.5f * v * (1.0f + erff(v * 0.70710678118654752f));
        if constexpr (EPI == EPI_RES) {
          if constexpr (__is_same(RT, float))
            v += Res[(size_t)row * N + col];
          else
            v += b2f(Res[(size_t)row * N + col]);
        }
        if constexpr (__is_same(CT, float))
          C[(size_t)row * N + col] = v;
        else
          C[(size_t)row * N + col] = f2b(v);
      }
    }
  }
}

// ---------------------------------------------------------------------------
// Q-projection GEMM writing attention layout directly (pre-scaled):
//   Qa[b][wi][nh][qi][hd] = (s @ Wq^T + bq)[b, l, c] * SCALE
//   l = nh*2048 + hd*64 + qi*16 + hi, wi = hi*256 + c.
// Same counted-vmcnt pipeline (f32-A path), NT=4.
// ---------------------------------------------------------------------------
__global__ void __launch_bounds__(256, 2) gemm_q(
    const float* __restrict__ A, const BF* __restrict__ Bw,
    const float* __restrict__ bias, BF* __restrict__ Qa) {
  constexpr int K = 256;
  alignas(16) __shared__ BF As[2][8][128][8];
  alignas(16) __shared__ BF Bs[2][8][128][8];
  const int cpx = gridDim.x >> 3;
  const int bid = blockIdx.x;
  const int swz = (bid & 7) * cpx + (bid >> 3);
  const int mt = swz >> 1, nt = swz & 1;
  const int hp = mt & 3, qi = (mt >> 2) & 3, nh = (mt >> 4) & 7, bb = mt >> 7;
  const int col0 = nt << 7;
  const int t = threadIdx.x;
  const int wave = t >> 6, lane = t & 63;
  const int wr = wave >> 1, wc = wave & 1;
  const int sm = t & 127;
  const int skc = t >> 7;
  const size_t grow = (size_t)bb * 16384 + nh * 2048 + (size_t)(sm & 31) * 64 +
                      qi * 16 + hp * 4 + (sm >> 5);
  f32x4 acc[4][4] = {};
  float4 ar[4][2];

  auto stageB = [&](int kt, int d) {
#pragma unroll
    for (int i = 0; i < 4; ++i) {
      const int kc = i * 2 + skc;
      gld_lds16(Bw + (size_t)(col0 + sm) * K + kt * 64 + kc * 8,
                &Bs[d][0][0][0] + (size_t)(i * 256 + wave * 64) * 8);
    }
  };
  auto loadA = [&](int kt) {
#pragma unroll
    for (int i = 0; i < 4; ++i) {
      const int kc = i * 2 + skc;
      const float* src = A + grow * K + kt * 64 + kc * 8;
      ar[i][0] = ((const float4*)src)[0];
      ar[i][1] = ((const float4*)src)[1];
    }
  };
  auto writeA = [&](int d) {
#pragma unroll
    for (int i = 0; i < 4; ++i) {
      const int kc = i * 2 + skc;
      BF tmp[8];
      tmp[0] = f2b(ar[i][0].x); tmp[1] = f2b(ar[i][0].y);
      tmp[2] = f2b(ar[i][0].z); tmp[3] = f2b(ar[i][0].w);
      tmp[4] = f2b(ar[i][1].x); tmp[5] = f2b(ar[i][1].y);
      tmp[6] = f2b(ar[i][1].z); tmp[7] = f2b(ar[i][1].w);
      *(bf16x8*)(&As[d][kc][sm][0]) = *(bf16x8*)tmp;
    }
  };
  auto compute = [&](int d) {
#pragma unroll
    for (int kk = 0; kk < 2; ++kk) {
      const int chunk = kk * 4 + (lane >> 4);
      const int rl = lane & 15;
      bf16x8 af[4], bfr[4];
#pragma unroll
      for (int mi = 0; mi < 4; ++mi)
        af[mi] = *(const bf16x8*)(&As[d][chunk][wr * 64 + mi * 16 + rl][0]);
#pragma unroll
      for (int ni = 0; ni < 4; ++ni)
        bfr[ni] = *(const bf16x8*)(&Bs[d][chunk][wc * 64 + ni * 16 + rl][0]);
#pragma unroll
      for (int mi = 0; mi < 4; ++mi)
#pragma unroll
        for (int ni = 0; ni < 4; ++ni)
          acc[mi][ni] = __builtin_amdgcn_mfma_f32_16x16x32_bf16(
              af[mi], bfr[ni], acc[mi][ni], 0, 0, 0);
    }
  };

  stageB(0, 0);
  loadA(0);
  for (int kt = 0; kt < 4; ++kt) {
    const int cur = kt & 1, nxt = cur ^ 1;
    const bool more = kt + 1 < 4;
    writeA(cur);
    if (more) {
      stageB(kt + 1, nxt);
      loadA(kt + 1);
      asm volatile("s_waitcnt vmcnt(12) lgkmcnt(0)" ::: "memory");
    } else {
      asm volatile("s_waitcnt vmcnt(0) lgkmcnt(0)" ::: "memory");
    }
    __builtin_amdgcn_s_barrier();
    __builtin_amdgcn_sched_barrier(0);
    compute(cur);
    __builtin_amdgcn_s_barrier();
  }

  const int rl = lane & 15, rg = lane >> 4;
  const float SCALE = 0.17677669529663689f;  // 32^-0.5
#pragma unroll
  for (int mi = 0; mi < 4; ++mi) {
#pragma unroll
    for (int ni = 0; ni < 4; ++ni) {
      const int col = col0 + wc * 64 + ni * 16 + rl;
      const float bcol = bias[col];
      const int i0 = wr * 64 + mi * 16 + rg * 4;
      const int hd = i0 & 31, hil = i0 >> 5;
      const int wi = (hp * 4 + hil) * 256 + col;
      BF4 pk;
#pragma unroll
      for (int r = 0; r < 4; ++r)
        pk.v[r] = f2b((acc[mi][ni][r] + bcol) * SCALE);
      *(BF4*)(Qa + ((((size_t)bb * 4096 + wi) * 8 + nh) * 128 + qi * 32 + hd)) = pk;
    }
  }
}

// ---------------------------------------------------------------------------
// Windowed attention v3: no LDS, no QK shuffles. 16-lane group per (w,nh),
// lane = qi*4+kj. q from Qa (hd-contig, pre-scaled), k/v from KV512
// (row l_x = kj*4096+wi; cols [0:256)=K, [256:512)=V; hd-contig 64B runs).
// ---------------------------------------------------------------------------
__global__ void __launch_bounds__(256) attn_kernel(
    const BF* __restrict__ Qa, const BF* __restrict__ KV,
    const float* __restrict__ biasb, BF* __restrict__ O) {
  const int t = threadIdx.x;
  const int g = t >> 4, l16 = t & 15;
  const int qi = l16 >> 2, kj = l16 & 3;
  const int w = (blockIdx.x << 1) | (g >> 3);
  const int nh = g & 7;
  const int b = w >> 12, wi = w & 4095;

  const uint4* qp = (const uint4*)(Qa + ((((size_t)b * 4096 + wi) * 8 + nh) * 128 + qi * 32));
  uint4 qv[4] = {qp[0], qp[1], qp[2], qp[3]};
  const uint4* kp = (const uint4*)(KV + ((size_t)b * 16384 + kj * 4096 + wi) * 512 + nh * 32);
  uint4 kv[4] = {kp[0], kp[1], kp[2], kp[3]};
  const float bias_l = biasb[(size_t)w * 128 + nh * 16 + l16];
  const BF* vbase = KV + (size_t)b * 16384 * 512 + 256 + nh * 32 + kj * 8;
  uint4 vv[4];
#pragma unroll
  for (int d = 0; d < 4; ++d)
    vv[d] = *(const uint4*)(vbase + ((size_t)((kj ^ d) * 4096 + wi)) * 512);

  float accs[4] = {0.f, 0.f, 0.f, 0.f};
#pragma unroll
  for (int j = 0; j < 4; ++j) {
#pragma unroll
    for (int e = 0; e < 4; ++e) {
      unsigned qe = ((const unsigned*)&qv[j])[e];
      unsigned ke = ((const unsigned*)&kv[j])[e];
      float ql = __uint_as_float(qe << 16);
      float qh = __uint_as_float(qe & 0xffff0000u);
      float kl = __uint_as_float(ke << 16);
      float kh = __uint_as_float(ke & 0xffff0000u);
      accs[e] = fmaf(ql, kl, accs[e]);
      accs[e] = fmaf(qh, kh, accs[e]);
    }
  }
  const float score = accs[0] + accs[1] + accs[2] + accs[3] + bias_l;

  float mx = fmaxf(score, __shfl_xor(score, 1));
  mx = fmaxf(mx, __shfl_xor(mx, 2));
  float e = __expf(score - mx);
  float sm = e + __shfl_xor(e, 1);
  sm += __shfl_xor(sm, 2);
  float p = e / sm;
  float pd[4];
  pd[0] = p;
  pd[1] = __shfl_xor(p, 1);
  pd[2] = __shfl_xor(p, 2);
  pd[3] = __shfl_xor(pd[1], 2);

  float o8[8] = {0.f, 0.f, 0.f, 0.f, 0.f, 0.f, 0.f, 0.f};
#pragma unroll
  for (int d = 0; d < 4; ++d) {
#pragma unroll
    for (int e2 = 0; e2 < 4; ++e2) {
      unsigned ve = ((const unsigned*)&vv[d])[e2];
      o8[e2 * 2 + 0] = fmaf(pd[d], __uint_as_float(ve << 16), o8[e2 * 2 + 0]);
      o8[e2 * 2 + 1] = fmaf(pd[d], __uint_as_float(ve & 0xffff0000u), o8[e2 * 2 + 1]);
    }
  }
  BF8 ob;
#pragma unroll
  for (int h = 0; h < 8; ++h) ob.v[h] = f2b(o8[h]);
  *(BF8*)(O + ((size_t)b * 16384 + qi * 4096 + wi) * 256 + nh * 32 + kj * 8) = ob;
}

// ---------------------------------------------------------------------------
// LayerNorm over C=256: one 64-lane wave per row, 4 bf16 per lane.
// ---------------------------------------------------------------------------
__global__ void __launch_bounds__(256) ln_kernel(
    const BF* __restrict__ S1, const float* __restrict__ g,
    const float* __restrict__ be, BF* __restrict__ Nout) {
  const int wave = threadIdx.x >> 6, lane = threadIdx.x & 63;
  const size_t row = (size_t)blockIdx.x * 4 + wave;
  BF4 d = *(const BF4*)(S1 + row * 256 + lane * 4);
  float x[4] = {b2f(d.v[0]), b2f(d.v[1]), b2f(d.v[2]), b2f(d.v[3])};
  float s = x[0] + x[1] + x[2] + x[3];
  float sq = x[0] * x[0] + x[1] * x[1] + x[2] * x[2] + x[3] * x[3];
#pragma unroll
  for (int m = 1; m <= 32; m <<= 1) {
    s += __shfl_xor(s, m);
    sq += __shfl_xor(sq, m);
  }
  const float mean = s * 0.00390625f;
  const float var = sq * 0.00390625f - mean * mean;
  const float rstd = 1.0f / sqrtf(var + 1e-5f);
  BF4 o;
#pragma unroll
  for (int jj = 0; jj < 4; ++jj) {
    float nv = (x[jj] - mean) * rstd * g[lane * 4 + jj] + be[lane * 4 + jj];
    o.v[jj] = f2b(nv);
  }
  *(BF4*)(Nout + row * 256 + lane * 4) = o;
}

// ---------------------------------------------------------------------------
// ws layout (bytes):
//   [0,          8388608)   rel-bias f32 (nW*128)
//   [8388608,    41943040)  Qa bf16 [b][wi][nh][qi][hd] -> LN out after attn
//   [41943040,  109051904)  KV512 bf16 (65536 x 512; K|V halves) -> H2 after
//   [109051904, 142606336)  S1 bf16
//   [142606336, ~144.2MB)   bf16 weights Wq,Wo, Wkv(stacked), mw1, mw2; bkv f32
// d_out doubles as bf16 attn-output staging (consumed by Wo-GEMM, then
// overwritten with final f32 by MLP2).
// ---------------------------------------------------------------------------
extern "C" void kernel_launch(void* const* d_in, const int* in_sizes, int n_in,
                              void* d_out, int out_size, void* d_ws, size_t ws_size,
                              hipStream_t stream) {
  const float* s     = (const float*)d_in[0];
  const float* x     = (const float*)d_in[1];
  const float* s_pos = (const float*)d_in[2];
  const float* x_pos = (const float*)d_in[3];
  const float* Wq = (const float*)d_in[4];  const float* bq = (const float*)d_in[5];
  const float* Wk = (const float*)d_in[6];  const float* bk = (const float*)d_in[7];
  const float* Wv = (const float*)d_in[8];  const float* bv = (const float*)d_in[9];
  const float* Wo = (const float*)d_in[10]; const float* bo = (const float*)d_in[11];
  const float* pw1 = (const float*)d_in[12]; const float* pb1 = (const float*)d_in[13];
  const float* bn_g = (const float*)d_in[14]; const float* bn_b = (const float*)d_in[15];
  const float* bn_m = (const float*)d_in[16]; const float* bn_v = (const float*)d_in[17];
  const float* pw2 = (const float*)d_in[18]; const float* pb2 = (const float*)d_in[19];
  const float* ln_g = (const float*)d_in[20]; const float* ln_b = (const float*)d_in[21];
  const float* mw1 = (const float*)d_in[22]; const float* mb1 = (const float*)d_in[23];
  const float* mw2 = (const float*)d_in[24]; const float* mb2 = (const float*)d_in[25];

  char* ws = (char*)d_ws;
  float* biasb = (float*)ws;
  BF* Qa   = (BF*)(ws + 8388608);
  BF* KVw  = (BF*)(ws + 41943040);
  BF* S1   = (BF*)(ws + 109051904);
  BF* Wq_bf  = (BF*)(ws + 142606336);
  BF* Wo_bf  = (BF*)(ws + 142737408);
  BF* Wkv_bf = (BF*)(ws + 142868480);
  BF* mw1_bf = (BF*)(ws + 143130624);
  BF* mw2_bf = (BF*)(ws + 143654912);
  float* bkv = (float*)(ws + 144179200);
  BF* Nw = Qa;            // LN output reuses Qa region (free after attn)
  BF* H2 = KVw;           // MLP hidden reuses KV region (free after attn)
  BF* ObBF = (BF*)d_out;  // attn output staged bf16 inside d_out
  float* Of = (float*)d_out;

  cvt_kernel<<<64, 256, 0, stream>>>(Wq, Wq_bf, 16384);
  cvt_kernel<<<64, 256, 0, stream>>>(Wo, Wo_bf, 16384);
  cvt_kernel<<<64, 256, 0, stream>>>(Wk, Wkv_bf, 16384);
  cvt_kernel<<<64, 256, 0, stream>>>(Wv, Wkv_bf + 65536, 16384);
  cvt_kernel<<<256, 256, 0, stream>>>(mw1, mw1_bf, 65536);
  cvt_kernel<<<256, 256, 0, stream>>>(mw2, mw2_bf, 65536);
  bkv_kernel<<<2, 256, 0, stream>>>(bk, bv, bkv);
  bias_kernel<<<1024, 256, 0, stream>>>(s_pos, x_pos, pw1, pb1, bn_g, bn_b,
                                        bn_m, bn_v, pw2, pb2, biasb);

  gemm_q<<<1024, 256, 0, stream>>>(s, Wq_bf, bq, Qa);
  gemm_tn<EPI_NONE, float, float, BF><<<2048, 256, 0, stream>>>(
      x, Wkv_bf, bkv, nullptr, KVw, 65536, 512, 256);
  attn_kernel<<<8192, 256, 0, stream>>>(Qa, KVw, biasb, ObBF);
  gemm_tn<EPI_RES, BF, float, BF><<<1024, 256, 0, stream>>>(
      ObBF, Wo_bf, bo, s, S1, 65536, 256, 256);
  ln_kernel<<<16384, 256, 0, stream>>>(S1, ln_g, ln_b, Nw);
  for (int h = 0; h < 2; ++h) {
    const size_t ro = (size_t)h * 32768;
    gemm_tn<EPI_GELU, BF, float, BF><<<2048, 256, 0, stream>>>(
        Nw + ro * 256, mw1_bf, mb1, nullptr, H2, 32768, 1024, 256);
    gemm_tn<EPI_RES, BF, BF, float><<<512, 256, 0, stream>>>(
        H2, mw2_bf, mb2, S1 + ro * 256, Of + ro * 256, 32768, 256, 1024);
  }
}

// Round 7
// 408.407 us; speedup vs baseline: 1.0660x; 1.0660x over previous
//
#include <hip/hip_runtime.h>
#include <hip/hip_bf16.h>
#include <math.h>

typedef __hip_bfloat16 BF;
typedef __bf16 bf16x8 __attribute__((ext_vector_type(8)));
typedef float f32x4 __attribute__((ext_vector_type(4)));

struct alignas(8) BF4 { BF v[4]; };
struct alignas(16) BF8 { BF v[8]; };

static __device__ __forceinline__ float b2f(BF x) { return __bfloat162float(x); }
static __device__ __forceinline__ BF f2b(float x) { return __float2bfloat16(x); }

// async global->LDS, 16B per lane; LDS dest = wave-uniform base (+lane*16 implicit)
static __device__ __forceinline__ void gld_lds16(const void* g, void* l) {
  __builtin_amdgcn_global_load_lds(
      (const __attribute__((address_space(1))) unsigned int*)g,
      (__attribute__((address_space(3))) unsigned int*)l, 16, 0, 0);
}

// ---------------------------------------------------------------------------
// f32 -> bf16 convert, 4 elements/thread, grid-stride
// ---------------------------------------------------------------------------
__global__ void __launch_bounds__(256) cvt_kernel(
    const float* __restrict__ in, BF* __restrict__ out, int n4) {
  for (int i = blockIdx.x * 256 + threadIdx.x; i < n4; i += gridDim.x * 256) {
    float4 v = ((const float4*)in)[i];
    BF4 o;
    o.v[0] = f2b(v.x); o.v[1] = f2b(v.y); o.v[2] = f2b(v.z); o.v[3] = f2b(v.w);
    ((BF4*)out)[i] = o;
  }
}

// concat bk||bv -> bkv (f32), 2 blocks x 256
__global__ void __launch_bounds__(256) bkv_kernel(
    const float* __restrict__ bk, const float* __restrict__ bv,
    float* __restrict__ bkv) {
  int i = blockIdx.x * 256 + threadIdx.x;
  bkv[i] = (i < 256) ? bk[i] : bv[i - 256];
}

// ---------------------------------------------------------------------------
// rel-bias kernel: one thread per (window w, l=qi*4+kj). out[w*128+nh*16+l], f32
// ---------------------------------------------------------------------------
__global__ void __launch_bounds__(256) bias_kernel(
    const float* __restrict__ s_pos, const float* __restrict__ x_pos,
    const float* __restrict__ pw1, const float* __restrict__ pb1,
    const float* __restrict__ bn_g, const float* __restrict__ bn_b,
    const float* __restrict__ bn_m, const float* __restrict__ bn_v,
    const float* __restrict__ pw2, const float* __restrict__ pb2,
    float* __restrict__ out) {
  int gid = blockIdx.x * 256 + threadIdx.x;   // [0, 16384*16)
  int w = gid >> 4, l = gid & 15;
  int b = w >> 12, wi = w & 4095;
  int i = l >> 2, j = l & 3;
  int e0 = i, e1 = 4 + i;
  float sp0 = s_pos[(((size_t)b * 2 + (e0 & 1)) * 4096 + wi) * 4 + (e0 >> 1)];
  float sp1 = s_pos[(((size_t)b * 2 + (e1 & 1)) * 4096 + wi) * 4 + (e1 >> 1)];
  float xp0 = x_pos[((size_t)b * 16384 + j * 4096 + wi) * 2 + 0];
  float xp1 = x_pos[((size_t)b * 16384 + j * 4096 + wi) * 2 + 1];
  float r0 = sp0 - xp0, r1 = sp1 - xp1;
  float acc[8];
#pragma unroll
  for (int p = 0; p < 8; ++p) acc[p] = pb2[p];
#pragma unroll
  for (int o = 0; o < 16; ++o) {
    float t = pw1[o * 2 + 0] * r0 + pw1[o * 2 + 1] * r1 + pb1[o];
    float sc = bn_g[o] / sqrtf(bn_v[o] + 1e-5f);
    t = (t - bn_m[o]) * sc + bn_b[o];
    t = fmaxf(t, 0.0f);
#pragma unroll
    for (int p = 0; p < 8; ++p) acc[p] += pw2[p * 16 + o] * t;
  }
#pragma unroll
  for (int p = 0; p < 8; ++p) out[(size_t)w * 128 + p * 16 + l] = acc[p];
}

// ---------------------------------------------------------------------------
// TN bf16 MFMA GEMM, single-buffer LDS (32KB), m97 2-barrier structure +
// A-register prefetch (f32 path). C = epi(A @ Bw^T + bias). 128x128 tile,
// BK=64, 4 waves 2x2, 16x16x32 MFMA, bijective XCD swizzle.
// __launch_bounds__(256,4): waves/EU >= 4 (VGPR budget <=128); R0-R5 carried
// ",2" which pinned occupancy at ~8 waves/CU across ALL LDS configs -> the
// GEMMs were latency-bound at 20-28% occupancy regardless of schedule.
// ---------------------------------------------------------------------------
enum { EPI_NONE = 0, EPI_RES = 1, EPI_GELU = 2 };

template <int EPI, typename AT, typename RT, typename CT>
__global__ void __launch_bounds__(256, 4) gemm_tn(
    const AT* __restrict__ A, const BF* __restrict__ Bw,
    const float* __restrict__ bias, const RT* __restrict__ Res,
    CT* __restrict__ C, int M, int N, int K) {
  constexpr bool F32A = __is_same(AT, float);
  alignas(16) __shared__ BF As[8][128][8];
  alignas(16) __shared__ BF Bs[8][128][8];
  const int ntiles = N >> 7;
  const int cpx = gridDim.x >> 3;
  const int bid = blockIdx.x;
  const int swz = (bid & 7) * cpx + (bid >> 3);   // XCD-chunked, bijective
  const int mt = swz / ntiles, nt = swz % ntiles;
  const int row0 = mt << 7, col0 = nt << 7;
  const int t = threadIdx.x;
  const int wave = t >> 6, lane = t & 63;
  const int wr = wave >> 1, wc = wave & 1;
  const int sm = t & 127;      // staging row within tile
  const int skc = t >> 7;      // staging k-chunk parity
  f32x4 acc[4][4] = {};
  const int NT = K >> 6;
  float4 ar[4][2];

  auto stageB = [&](int kt) {
#pragma unroll
    for (int i = 0; i < 4; ++i) {
      const int kc = i * 2 + skc;
      gld_lds16(Bw + (size_t)(col0 + sm) * K + kt * 64 + kc * 8,
                &Bs[0][0][0] + (size_t)(i * 256 + wave * 64) * 8);
    }
  };
  auto loadA = [&](int kt) {
    if constexpr (F32A) {
#pragma unroll
      for (int i = 0; i < 4; ++i) {
        const int kc = i * 2 + skc;
        const float* src = A + (size_t)(row0 + sm) * K + kt * 64 + kc * 8;
        ar[i][0] = ((const float4*)src)[0];
        ar[i][1] = ((const float4*)src)[1];
      }
    }
  };
  auto writeA = [&]() {
    if constexpr (F32A) {
#pragma unroll
      for (int i = 0; i < 4; ++i) {
        const int kc = i * 2 + skc;
        BF tmp[8];
        tmp[0] = f2b(ar[i][0].x); tmp[1] = f2b(ar[i][0].y);
        tmp[2] = f2b(ar[i][0].z); tmp[3] = f2b(ar[i][0].w);
        tmp[4] = f2b(ar[i][1].x); tmp[5] = f2b(ar[i][1].y);
        tmp[6] = f2b(ar[i][1].z); tmp[7] = f2b(ar[i][1].w);
        *(bf16x8*)(&As[kc][sm][0]) = *(bf16x8*)tmp;
      }
    }
  };
  auto stageA_bf = [&](int kt) {
    if constexpr (!F32A) {
#pragma unroll
      for (int i = 0; i < 4; ++i) {
        const int kc = i * 2 + skc;
        gld_lds16((const BF*)A + (size_t)(row0 + sm) * K + kt * 64 + kc * 8,
                  &As[0][0][0] + (size_t)(i * 256 + wave * 64) * 8);
      }
    }
  };
  auto compute = [&]() {
#pragma unroll
    for (int kk = 0; kk < 2; ++kk) {
      const int chunk = kk * 4 + (lane >> 4);
      const int rl = lane & 15;
      bf16x8 af[4], bfr[4];
#pragma unroll
      for (int mi = 0; mi < 4; ++mi)
        af[mi] = *(const bf16x8*)(&As[chunk][wr * 64 + mi * 16 + rl][0]);
#pragma unroll
      for (int ni = 0; ni < 4; ++ni)
        bfr[ni] = *(const bf16x8*)(&Bs[chunk][wc * 64 + ni * 16 + rl][0]);
#pragma unroll
      for (int mi = 0; mi < 4; ++mi)
#pragma unroll
        for (int ni = 0; ni < 4; ++ni)
          acc[mi][ni] = __builtin_amdgcn_mfma_f32_16x16x32_bf16(
              af[mi], bfr[ni], acc[mi][ni], 0, 0, 0);
    }
  };

  loadA(0);
  for (int kt = 0; kt < NT; ++kt) {
    writeA();                       // f32 path: regs(kt) -> LDS
    stageA_bf(kt);                  // bf16 path: global -> LDS direct
    stageB(kt);
    if (kt + 1 < NT) loadA(kt + 1); // prefetch next A to regs
    __syncthreads();                // stage visible
    compute();
    __syncthreads();                // compute done before LDS overwrite
  }

  // epilogue: D layout col = lane&15, row = (lane>>4)*4 + r (m89-verified)
  const int rl = lane & 15, rg = lane >> 4;
#pragma unroll
  for (int mi = 0; mi < 4; ++mi) {
#pragma unroll
    for (int ni = 0; ni < 4; ++ni) {
      const int col = col0 + wc * 64 + ni * 16 + rl;
      const float bcol = bias[col];
#pragma unroll
      for (int r = 0; r < 4; ++r) {
        const int row = row0 + wr * 64 + mi * 16 + rg * 4 + r;
        float v = acc[mi][ni][r] + bcol;
        if constexpr (EPI == EPI_GELU)
          v = 0.5f * v * (1.0f + erff(v * 0.70710678118654752f));
        if constexpr (EPI == EPI_RES) {
          if constexpr (__is_same(RT, float))
            v += Res[(size_t)row * N + col];
          else
            v += b2f(Res[(size_t)row * N + col]);
        }
        if constexpr (__is_same(CT, float))
          C[(size_t)row * N + col] = v;
        else
          C[(size_t)row * N + col] = f2b(v);
      }
    }
  }
}

// ---------------------------------------------------------------------------
// Q-projection GEMM writing attention layout directly (pre-scaled):
//   Qa[b][wi][nh][qi][hd] = (s @ Wq^T + bq)[b, l, c] * SCALE
//   l = nh*2048 + hd*64 + qi*16 + hi, wi = hi*256 + c.
// Single-buffer LDS, same structure/occupancy bounds as gemm_tn.
// ---------------------------------------------------------------------------
__global__ void __launch_bounds__(256, 4) gemm_q(
    const float* __restrict__ A, const BF* __restrict__ Bw,
    const float* __restrict__ bias, BF* __restrict__ Qa) {
  constexpr int K = 256;
  alignas(16) __shared__ BF As[8][128][8];
  alignas(16) __shared__ BF Bs[8][128][8];
  const int cpx = gridDim.x >> 3;
  const int bid = blockIdx.x;
  const int swz = (bid & 7) * cpx + (bid >> 3);
  const int mt = swz >> 1, nt = swz & 1;
  const int hp = mt & 3, qi = (mt >> 2) & 3, nh = (mt >> 4) & 7, bb = mt >> 7;
  const int col0 = nt << 7;
  const int t = threadIdx.x;
  const int wave = t >> 6, lane = t & 63;
  const int wr = wave >> 1, wc = wave & 1;
  const int sm = t & 127;
  const int skc = t >> 7;
  const size_t grow = (size_t)bb * 16384 + nh * 2048 + (size_t)(sm & 31) * 64 +
                      qi * 16 + hp * 4 + (sm >> 5);
  f32x4 acc[4][4] = {};
  float4 ar[4][2];

  auto stageB = [&](int kt) {
#pragma unroll
    for (int i = 0; i < 4; ++i) {
      const int kc = i * 2 + skc;
      gld_lds16(Bw + (size_t)(col0 + sm) * K + kt * 64 + kc * 8,
                &Bs[0][0][0] + (size_t)(i * 256 + wave * 64) * 8);
    }
  };
  auto loadA = [&](int kt) {
#pragma unroll
    for (int i = 0; i < 4; ++i) {
      const int kc = i * 2 + skc;
      const float* src = A + grow * K + kt * 64 + kc * 8;
      ar[i][0] = ((const float4*)src)[0];
      ar[i][1] = ((const float4*)src)[1];
    }
  };
  auto writeA = [&]() {
#pragma unroll
    for (int i = 0; i < 4; ++i) {
      const int kc = i * 2 + skc;
      BF tmp[8];
      tmp[0] = f2b(ar[i][0].x); tmp[1] = f2b(ar[i][0].y);
      tmp[2] = f2b(ar[i][0].z); tmp[3] = f2b(ar[i][0].w);
      tmp[4] = f2b(ar[i][1].x); tmp[5] = f2b(ar[i][1].y);
      tmp[6] = f2b(ar[i][1].z); tmp[7] = f2b(ar[i][1].w);
      *(bf16x8*)(&As[kc][sm][0]) = *(bf16x8*)tmp;
    }
  };
  auto compute = [&]() {
#pragma unroll
    for (int kk = 0; kk < 2; ++kk) {
      const int chunk = kk * 4 + (lane >> 4);
      const int rl = lane & 15;
      bf16x8 af[4], bfr[4];
#pragma unroll
      for (int mi = 0; mi < 4; ++mi)
        af[mi] = *(const bf16x8*)(&As[chunk][wr * 64 + mi * 16 + rl][0]);
#pragma unroll
      for (int ni = 0; ni < 4; ++ni)
        bfr[ni] = *(const bf16x8*)(&Bs[chunk][wc * 64 + ni * 16 + rl][0]);
#pragma unroll
      for (int mi = 0; mi < 4; ++mi)
#pragma unroll
        for (int ni = 0; ni < 4; ++ni)
          acc[mi][ni] = __builtin_amdgcn_mfma_f32_16x16x32_bf16(
              af[mi], bfr[ni], acc[mi][ni], 0, 0, 0);
    }
  };

  loadA(0);
  for (int kt = 0; kt < 4; ++kt) {
    writeA();
    stageB(kt);
    if (kt + 1 < 4) loadA(kt + 1);
    __syncthreads();
    compute();
    __syncthreads();
  }

  const int rl = lane & 15, rg = lane >> 4;
  const float SCALE = 0.17677669529663689f;  // 32^-0.5
#pragma unroll
  for (int mi = 0; mi < 4; ++mi) {
#pragma unroll
    for (int ni = 0; ni < 4; ++ni) {
      const int col = col0 + wc * 64 + ni * 16 + rl;
      const float bcol = bias[col];
      const int i0 = wr * 64 + mi * 16 + rg * 4;
      const int hd = i0 & 31, hil = i0 >> 5;
      const int wi = (hp * 4 + hil) * 256 + col;
      BF4 pk;
#pragma unroll
      for (int r = 0; r < 4; ++r)
        pk.v[r] = f2b((acc[mi][ni][r] + bcol) * SCALE);
      *(BF4*)(Qa + ((((size_t)bb * 4096 + wi) * 8 + nh) * 128 + qi * 32 + hd)) = pk;
    }
  }
}

// ---------------------------------------------------------------------------
// Windowed attention v3: no LDS, no QK shuffles. 16-lane group per (w,nh),
// lane = qi*4+kj. q from Qa (hd-contig, pre-scaled), k/v from KV512
// (row l_x = kj*4096+wi; cols [0:256)=K, [256:512)=V; hd-contig 64B runs).
// ---------------------------------------------------------------------------
__global__ void __launch_bounds__(256) attn_kernel(
    const BF* __restrict__ Qa, const BF* __restrict__ KV,
    const float* __restrict__ biasb, BF* __restrict__ O) {
  const int t = threadIdx.x;
  const int g = t >> 4, l16 = t & 15;
  const int qi = l16 >> 2, kj = l16 & 3;
  const int w = (blockIdx.x << 1) | (g >> 3);
  const int nh = g & 7;
  const int b = w >> 12, wi = w & 4095;

  const uint4* qp = (const uint4*)(Qa + ((((size_t)b * 4096 + wi) * 8 + nh) * 128 + qi * 32));
  uint4 qv[4] = {qp[0], qp[1], qp[2], qp[3]};
  const uint4* kp = (const uint4*)(KV + ((size_t)b * 16384 + kj * 4096 + wi) * 512 + nh * 32);
  uint4 kv[4] = {kp[0], kp[1], kp[2], kp[3]};
  const float bias_l = biasb[(size_t)w * 128 + nh * 16 + l16];
  const BF* vbase = KV + (size_t)b * 16384 * 512 + 256 + nh * 32 + kj * 8;
  uint4 vv[4];
#pragma unroll
  for (int d = 0; d < 4; ++d)
    vv[d] = *(const uint4*)(vbase + ((size_t)((kj ^ d) * 4096 + wi)) * 512);

  float accs[4] = {0.f, 0.f, 0.f, 0.f};
#pragma unroll
  for (int j = 0; j < 4; ++j) {
#pragma unroll
    for (int e = 0; e < 4; ++e) {
      unsigned qe = ((const unsigned*)&qv[j])[e];
      unsigned ke = ((const unsigned*)&kv[j])[e];
      float ql = __uint_as_float(qe << 16);
      float qh = __uint_as_float(qe & 0xffff0000u);
      float kl = __uint_as_float(ke << 16);
      float kh = __uint_as_float(ke & 0xffff0000u);
      accs[e] = fmaf(ql, kl, accs[e]);
      accs[e] = fmaf(qh, kh, accs[e]);
    }
  }
  const float score = accs[0] + accs[1] + accs[2] + accs[3] + bias_l;

  float mx = fmaxf(score, __shfl_xor(score, 1));
  mx = fmaxf(mx, __shfl_xor(mx, 2));
  float e = __expf(score - mx);
  float sm = e + __shfl_xor(e, 1);
  sm += __shfl_xor(sm, 2);
  float p = e / sm;
  float pd[4];
  pd[0] = p;
  pd[1] = __shfl_xor(p, 1);
  pd[2] = __shfl_xor(p, 2);
  pd[3] = __shfl_xor(pd[1], 2);

  float o8[8] = {0.f, 0.f, 0.f, 0.f, 0.f, 0.f, 0.f, 0.f};
#pragma unroll
  for (int d = 0; d < 4; ++d) {
#pragma unroll
    for (int e2 = 0; e2 < 4; ++e2) {
      unsigned ve = ((const unsigned*)&vv[d])[e2];
      o8[e2 * 2 + 0] = fmaf(pd[d], __uint_as_float(ve << 16), o8[e2 * 2 + 0]);
      o8[e2 * 2 + 1] = fmaf(pd[d], __uint_as_float(ve & 0xffff0000u), o8[e2 * 2 + 1]);
    }
  }
  BF8 ob;
#pragma unroll
  for (int h = 0; h < 8; ++h) ob.v[h] = f2b(o8[h]);
  *(BF8*)(O + ((size_t)b * 16384 + qi * 4096 + wi) * 256 + nh * 32 + kj * 8) = ob;
}

// ---------------------------------------------------------------------------
// LayerNorm over C=256: one 64-lane wave per row, 4 bf16 per lane.
// ---------------------------------------------------------------------------
__global__ void __launch_bounds__(256) ln_kernel(
    const BF* __restrict__ S1, const float* __restrict__ g,
    const float* __restrict__ be, BF* __restrict__ Nout) {
  const int wave = threadIdx.x >> 6, lane = threadIdx.x & 63;
  const size_t row = (size_t)blockIdx.x * 4 + wave;
  BF4 d = *(const BF4*)(S1 + row * 256 + lane * 4);
  float x[4] = {b2f(d.v[0]), b2f(d.v[1]), b2f(d.v[2]), b2f(d.v[3])};
  float s = x[0] + x[1] + x[2] + x[3];
  float sq = x[0] * x[0] + x[1] * x[1] + x[2] * x[2] + x[3] * x[3];
#pragma unroll
  for (int m = 1; m <= 32; m <<= 1) {
    s += __shfl_xor(s, m);
    sq += __shfl_xor(sq, m);
  }
  const float mean = s * 0.00390625f;
  const float var = sq * 0.00390625f - mean * mean;
  const float rstd = 1.0f / sqrtf(var + 1e-5f);
  BF4 o;
#pragma unroll
  for (int jj = 0; jj < 4; ++jj) {
    float nv = (x[jj] - mean) * rstd * g[lane * 4 + jj] + be[lane * 4 + jj];
    o.v[jj] = f2b(nv);
  }
  *(BF4*)(Nout + row * 256 + lane * 4) = o;
}

// ---------------------------------------------------------------------------
// ws layout (bytes):
//   [0,          8388608)   rel-bias f32 (nW*128)
//   [8388608,    41943040)  Qa bf16 [b][wi][nh][qi][hd] -> LN out after attn
//   [41943040,  109051904)  KV512 bf16 (65536 x 512; K|V halves) -> H2 after
//   [109051904, 142606336)  S1 bf16
//   [142606336, ~144.2MB)   bf16 weights Wq,Wo, Wkv(stacked), mw1, mw2; bkv f32
// d_out doubles as bf16 attn-output staging (consumed by Wo-GEMM, then
// overwritten with final f32 by MLP2).
// ---------------------------------------------------------------------------
extern "C" void kernel_launch(void* const* d_in, const int* in_sizes, int n_in,
                              void* d_out, int out_size, void* d_ws, size_t ws_size,
                              hipStream_t stream) {
  const float* s     = (const float*)d_in[0];
  const float* x     = (const float*)d_in[1];
  const float* s_pos = (const float*)d_in[2];
  const float* x_pos = (const float*)d_in[3];
  const float* Wq = (const float*)d_in[4];  const float* bq = (const float*)d_in[5];
  const float* Wk = (const float*)d_in[6];  const float* bk = (const float*)d_in[7];
  const float* Wv = (const float*)d_in[8];  const float* bv = (const float*)d_in[9];
  const float* Wo = (const float*)d_in[10]; const float* bo = (const float*)d_in[11];
  const float* pw1 = (const float*)d_in[12]; const float* pb1 = (const float*)d_in[13];
  const float* bn_g = (const float*)d_in[14]; const float* bn_b = (const float*)d_in[15];
  const float* bn_m = (const float*)d_in[16]; const float* bn_v = (const float*)d_in[17];
  const float* pw2 = (const float*)d_in[18]; const float* pb2 = (const float*)d_in[19];
  const float* ln_g = (const float*)d_in[20]; const float* ln_b = (const float*)d_in[21];
  const float* mw1 = (const float*)d_in[22]; const float* mb1 = (const float*)d_in[23];
  const float* mw2 = (const float*)d_in[24]; const float* mb2 = (const float*)d_in[25];

  char* ws = (char*)d_ws;
  float* biasb = (float*)ws;
  BF* Qa   = (BF*)(ws + 8388608);
  BF* KVw  = (BF*)(ws + 41943040);
  BF* S1   = (BF*)(ws + 109051904);
  BF* Wq_bf  = (BF*)(ws + 142606336);
  BF* Wo_bf  = (BF*)(ws + 142737408);
  BF* Wkv_bf = (BF*)(ws + 142868480);
  BF* mw1_bf = (BF*)(ws + 143130624);
  BF* mw2_bf = (BF*)(ws + 143654912);
  float* bkv = (float*)(ws + 144179200);
  BF* Nw = Qa;            // LN output reuses Qa region (free after attn)
  BF* H2 = KVw;           // MLP hidden reuses KV region (free after attn)
  BF* ObBF = (BF*)d_out;  // attn output staged bf16 inside d_out
  float* Of = (float*)d_out;

  cvt_kernel<<<64, 256, 0, stream>>>(Wq, Wq_bf, 16384);
  cvt_kernel<<<64, 256, 0, stream>>>(Wo, Wo_bf, 16384);
  cvt_kernel<<<64, 256, 0, stream>>>(Wk, Wkv_bf, 16384);
  cvt_kernel<<<64, 256, 0, stream>>>(Wv, Wkv_bf + 65536, 16384);
  cvt_kernel<<<256, 256, 0, stream>>>(mw1, mw1_bf, 65536);
  cvt_kernel<<<256, 256, 0, stream>>>(mw2, mw2_bf, 65536);
  bkv_kernel<<<2, 256, 0, stream>>>(bk, bv, bkv);
  bias_kernel<<<1024, 256, 0, stream>>>(s_pos, x_pos, pw1, pb1, bn_g, bn_b,
                                        bn_m, bn_v, pw2, pb2, biasb);

  gemm_q<<<1024, 256, 0, stream>>>(s, Wq_bf, bq, Qa);
  gemm_tn<EPI_NONE, float, float, BF><<<2048, 256, 0, stream>>>(
      x, Wkv_bf, bkv, nullptr, KVw, 65536, 512, 256);
  attn_kernel<<<8192, 256, 0, stream>>>(Qa, KVw, biasb, ObBF);
  gemm_tn<EPI_RES, BF, float, BF><<<1024, 256, 0, stream>>>(
      ObBF, Wo_bf, bo, s, S1, 65536, 256, 256);
  ln_kernel<<<16384, 256, 0, stream>>>(S1, ln_g, ln_b, Nw);
  for (int h = 0; h < 2; ++h) {
    const size_t ro = (size_t)h * 32768;
    gemm_tn<EPI_GELU, BF, float, BF><<<2048, 256, 0, stream>>>(
        Nw + ro * 256, mw1_bf, mb1, nullptr, H2, 32768, 1024, 256);
    gemm_tn<EPI_RES, BF, BF, float><<<512, 256, 0, stream>>>(
        H2, mw2_bf, mb2, S1 + ro * 256, Of + ro * 256, 32768, 256, 1024);
  }
}

// Round 8
// 400.118 us; speedup vs baseline: 1.0880x; 1.0207x over previous
//
#include <hip/hip_runtime.h>
#include <hip/hip_bf16.h>
#include <math.h>

typedef __hip_bfloat16 BF;
typedef __bf16 bf16x8 __attribute__((ext_vector_type(8)));
typedef float f32x4 __attribute__((ext_vector_type(4)));

struct alignas(8) BF4 { BF v[4]; };
struct alignas(16) BF8 { BF v[8]; };

static __device__ __forceinline__ float b2f(BF x) { return __bfloat162float(x); }
static __device__ __forceinline__ BF f2b(float x) { return __float2bfloat16(x); }

// async global->LDS, 16B per lane; LDS dest = wave-uniform base (+lane*16 implicit)
static __device__ __forceinline__ void gld_lds16(const void* g, void* l) {
  __builtin_amdgcn_global_load_lds(
      (const __attribute__((address_space(1))) unsigned int*)g,
      (__attribute__((address_space(3))) unsigned int*)l, 16, 0, 0);
}

// ---------------------------------------------------------------------------
// f32 -> bf16 convert, 4 elements/thread, grid-stride
// ---------------------------------------------------------------------------
__global__ void __launch_bounds__(256) cvt_kernel(
    const float* __restrict__ in, BF* __restrict__ out, int n4) {
  for (int i = blockIdx.x * 256 + threadIdx.x; i < n4; i += gridDim.x * 256) {
    float4 v = ((const float4*)in)[i];
    BF4 o;
    o.v[0] = f2b(v.x); o.v[1] = f2b(v.y); o.v[2] = f2b(v.z); o.v[3] = f2b(v.w);
    ((BF4*)out)[i] = o;
  }
}

// concat bk||bv -> bkv (f32), 2 blocks x 256
__global__ void __launch_bounds__(256) bkv_kernel(
    const float* __restrict__ bk, const float* __restrict__ bv,
    float* __restrict__ bkv) {
  int i = blockIdx.x * 256 + threadIdx.x;
  bkv[i] = (i < 256) ? bk[i] : bv[i - 256];
}

// ---------------------------------------------------------------------------
// rel-bias kernel: one thread per (window w, l=qi*4+kj). out[w*128+nh*16+l], f32
// ---------------------------------------------------------------------------
__global__ void __launch_bounds__(256) bias_kernel(
    const float* __restrict__ s_pos, const float* __restrict__ x_pos,
    const float* __restrict__ pw1, const float* __restrict__ pb1,
    const float* __restrict__ bn_g, const float* __restrict__ bn_b,
    const float* __restrict__ bn_m, const float* __restrict__ bn_v,
    const float* __restrict__ pw2, const float* __restrict__ pb2,
    float* __restrict__ out) {
  int gid = blockIdx.x * 256 + threadIdx.x;   // [0, 16384*16)
  int w = gid >> 4, l = gid & 15;
  int b = w >> 12, wi = w & 4095;
  int i = l >> 2, j = l & 3;
  int e0 = i, e1 = 4 + i;
  float sp0 = s_pos[(((size_t)b * 2 + (e0 & 1)) * 4096 + wi) * 4 + (e0 >> 1)];
  float sp1 = s_pos[(((size_t)b * 2 + (e1 & 1)) * 4096 + wi) * 4 + (e1 >> 1)];
  float xp0 = x_pos[((size_t)b * 16384 + j * 4096 + wi) * 2 + 0];
  float xp1 = x_pos[((size_t)b * 16384 + j * 4096 + wi) * 2 + 1];
  float r0 = sp0 - xp0, r1 = sp1 - xp1;
  float acc[8];
#pragma unroll
  for (int p = 0; p < 8; ++p) acc[p] = pb2[p];
#pragma unroll
  for (int o = 0; o < 16; ++o) {
    float t = pw1[o * 2 + 0] * r0 + pw1[o * 2 + 1] * r1 + pb1[o];
    float sc = bn_g[o] / sqrtf(bn_v[o] + 1e-5f);
    t = (t - bn_m[o]) * sc + bn_b[o];
    t = fmaxf(t, 0.0f);
#pragma unroll
    for (int p = 0; p < 8; ++p) acc[p] += pw2[p * 16 + o] * t;
  }
#pragma unroll
  for (int p = 0; p < 8; ++p) out[(size_t)w * 128 + p * 16 + l] = acc[p];
}

// ---------------------------------------------------------------------------
// TN bf16 MFMA GEMM. Coalesced staging: each 8-lane group reads ONE row's
// contiguous 128B run (16 cachelines/instr vs 64 with the old lane->row map).
// LDS is row-major [128][64] bf16 with T2 XOR chunk swizzle: physical chunk
// p of row r holds logical chunk p^(r&7). Staging dest stays LINEAR (required
// by global_load_lds); the global SOURCE column is pre-swizzled — the swizzle
// reduces to the per-lane constant (lane&7)^(lane>>3), a permutation within
// the same 128B run, so coalescing is preserved. ds_read applies the same XOR
// (2-way bank aliasing = free). m97 2-barrier loop; 32KB LDS; (256,4).
// ---------------------------------------------------------------------------
enum { EPI_NONE = 0, EPI_RES = 1, EPI_GELU = 2 };

template <int EPI, typename AT, typename RT, typename CT>
__global__ void __launch_bounds__(256, 4) gemm_tn(
    const AT* __restrict__ A, const BF* __restrict__ Bw,
    const float* __restrict__ bias, const RT* __restrict__ Res,
    CT* __restrict__ C, int M, int N, int K) {
  constexpr bool F32A = __is_same(AT, float);
  alignas(16) __shared__ BF As[128 * 64];
  alignas(16) __shared__ BF Bs[128 * 64];
  const int ntiles = N >> 7;
  const int cpx = gridDim.x >> 3;
  const int bid = blockIdx.x;
  const int swz = (bid & 7) * cpx + (bid >> 3);   // XCD-chunked, bijective
  const int mt = swz / ntiles, nt = swz % ntiles;
  const int row0 = mt << 7, col0 = nt << 7;
  const int t = threadIdx.x;
  const int wave = t >> 6, lane = t & 63;
  const int wr = wave >> 1, wc = wave & 1;
  const int roct = t >> 3;                 // row-octet: 8 lanes share one row
  const int pch = t & 7;                   // physical 16B chunk within row
  const int schunk = pch ^ (roct & 7);     // pre-swizzled source chunk
  f32x4 acc[4][4] = {};
  const int NT = K >> 6;
  float4 ar[4][2];

  auto stageB = [&](int kt) {
#pragma unroll
    for (int i = 0; i < 4; ++i)
      gld_lds16(Bw + (size_t)(col0 + i * 32 + roct) * K + kt * 64 + schunk * 8,
                Bs + (i * 32 + wave * 8) * 64);
  };
  auto stageA_bf = [&](int kt) {
    if constexpr (!F32A) {
#pragma unroll
      for (int i = 0; i < 4; ++i)
        gld_lds16((const BF*)A + (size_t)(row0 + i * 32 + roct) * K + kt * 64 + schunk * 8,
                  As + (i * 32 + wave * 8) * 64);
    }
  };
  auto loadA = [&](int kt) {
    if constexpr (F32A) {
#pragma unroll
      for (int i = 0; i < 4; ++i) {
        const float* src = A + (size_t)(row0 + i * 32 + roct) * K + kt * 64 + schunk * 8;
        ar[i][0] = ((const float4*)src)[0];
        ar[i][1] = ((const float4*)src)[1];
      }
    }
  };
  auto writeA = [&]() {
    if constexpr (F32A) {
#pragma unroll
      for (int i = 0; i < 4; ++i) {
        BF tmp[8];
        tmp[0] = f2b(ar[i][0].x); tmp[1] = f2b(ar[i][0].y);
        tmp[2] = f2b(ar[i][0].z); tmp[3] = f2b(ar[i][0].w);
        tmp[4] = f2b(ar[i][1].x); tmp[5] = f2b(ar[i][1].y);
        tmp[6] = f2b(ar[i][1].z); tmp[7] = f2b(ar[i][1].w);
        // linear dest (conflict-free b128 write); data is source-swizzled
        *(bf16x8*)(As + (i * 32 + roct) * 64 + pch * 8) = *(bf16x8*)tmp;
      }
    }
  };
  auto compute = [&]() {
    const int rl = lane & 15, lg = lane >> 4;
#pragma unroll
    for (int kk = 0; kk < 2; ++kk) {
      const int pc = ((kk * 4 + lg) ^ (rl & 7)) << 3;  // swizzled chunk offset
      bf16x8 af[4], bfr[4];
#pragma unroll
      for (int mi = 0; mi < 4; ++mi)
        af[mi] = *(const bf16x8*)(As + (wr * 64 + mi * 16 + rl) * 64 + pc);
#pragma unroll
      for (int ni = 0; ni < 4; ++ni)
        bfr[ni] = *(const bf16x8*)(Bs + (wc * 64 + ni * 16 + rl) * 64 + pc);
#pragma unroll
      for (int mi = 0; mi < 4; ++mi)
#pragma unroll
        for (int ni = 0; ni < 4; ++ni)
          acc[mi][ni] = __builtin_amdgcn_mfma_f32_16x16x32_bf16(
              af[mi], bfr[ni], acc[mi][ni], 0, 0, 0);
    }
  };

  loadA(0);
  for (int kt = 0; kt < NT; ++kt) {
    writeA();                       // f32 path: regs(kt) -> LDS
    stageA_bf(kt);                  // bf16 path: global -> LDS direct
    stageB(kt);
    if (kt + 1 < NT) loadA(kt + 1); // prefetch next A to regs
    __syncthreads();                // stage visible
    compute();
    __syncthreads();                // compute done before LDS overwrite
  }

  // epilogue: D layout col = lane&15, row = (lane>>4)*4 + r (m89-verified)
  const int rl = lane & 15, rg = lane >> 4;
#pragma unroll
  for (int mi = 0; mi < 4; ++mi) {
#pragma unroll
    for (int ni = 0; ni < 4; ++ni) {
      const int col = col0 + wc * 64 + ni * 16 + rl;
      const float bcol = bias[col];
#pragma unroll
      for (int r = 0; r < 4; ++r) {
        const int row = row0 + wr * 64 + mi * 16 + rg * 4 + r;
        float v = acc[mi][ni][r] + bcol;
        if constexpr (EPI == EPI_GELU)
          v = 0.5f * v * (1.0f + erff(v * 0.70710678118654752f));
        if constexpr (EPI == EPI_RES) {
          if constexpr (__is_same(RT, float))
            v += Res[(size_t)row * N + col];
          else
            v += b2f(Res[(size_t)row * N + col]);
        }
        if constexpr (__is_same(CT, float))
          C[(size_t)row * N + col] = v;
        else
          C[(size_t)row * N + col] = f2b(v);
      }
    }
  }
}

// ---------------------------------------------------------------------------
// Q-projection GEMM writing attention layout directly (pre-scaled):
//   Qa[b][wi][nh][qi][hd] = (s @ Wq^T + bq)[b, l, c] * SCALE
//   l = nh*2048 + hd*64 + qi*16 + hi, wi = hi*256 + c.
// Same coalesced+swizzled staging as gemm_tn (tile rows are scattered in M,
// but each 8-lane group still reads one row's contiguous 128B run).
// ---------------------------------------------------------------------------
__global__ void __launch_bounds__(256, 4) gemm_q(
    const float* __restrict__ A, const BF* __restrict__ Bw,
    const float* __restrict__ bias, BF* __restrict__ Qa) {
  constexpr int K = 256;
  alignas(16) __shared__ BF As[128 * 64];
  alignas(16) __shared__ BF Bs[128 * 64];
  const int cpx = gridDim.x >> 3;
  const int bid = blockIdx.x;
  const int swz = (bid & 7) * cpx + (bid >> 3);
  const int mt = swz >> 1, nt = swz & 1;
  const int hp = mt & 3, qi = (mt >> 2) & 3, nh = (mt >> 4) & 7, bb = mt >> 7;
  const int col0 = nt << 7;
  const int t = threadIdx.x;
  const int wave = t >> 6, lane = t & 63;
  const int wr = wave >> 1, wc = wave & 1;
  const int roct = t >> 3;
  const int pch = t & 7;
  const int schunk = pch ^ (roct & 7);
  f32x4 acc[4][4] = {};
  float4 ar[4][2];

  auto growof = [&](int i) -> size_t {
    const int o = i * 32 + roct;   // tile row
    return (size_t)bb * 16384 + nh * 2048 + (size_t)(o & 31) * 64 +
           qi * 16 + hp * 4 + (o >> 5);
  };
  auto stageB = [&](int kt) {
#pragma unroll
    for (int i = 0; i < 4; ++i)
      gld_lds16(Bw + (size_t)(col0 + i * 32 + roct) * K + kt * 64 + schunk * 8,
                Bs + (i * 32 + wave * 8) * 64);
  };
  auto loadA = [&](int kt) {
#pragma unroll
    for (int i = 0; i < 4; ++i) {
      const float* src = A + growof(i) * K + kt * 64 + schunk * 8;
      ar[i][0] = ((const float4*)src)[0];
      ar[i][1] = ((const float4*)src)[1];
    }
  };
  auto writeA = [&]() {
#pragma unroll
    for (int i = 0; i < 4; ++i) {
      BF tmp[8];
      tmp[0] = f2b(ar[i][0].x); tmp[1] = f2b(ar[i][0].y);
      tmp[2] = f2b(ar[i][0].z); tmp[3] = f2b(ar[i][0].w);
      tmp[4] = f2b(ar[i][1].x); tmp[5] = f2b(ar[i][1].y);
      tmp[6] = f2b(ar[i][1].z); tmp[7] = f2b(ar[i][1].w);
      *(bf16x8*)(As + (i * 32 + roct) * 64 + pch * 8) = *(bf16x8*)tmp;
    }
  };
  auto compute = [&]() {
    const int rl = lane & 15, lg = lane >> 4;
#pragma unroll
    for (int kk = 0; kk < 2; ++kk) {
      const int pc = ((kk * 4 + lg) ^ (rl & 7)) << 3;
      bf16x8 af[4], bfr[4];
#pragma unroll
      for (int mi = 0; mi < 4; ++mi)
        af[mi] = *(const bf16x8*)(As + (wr * 64 + mi * 16 + rl) * 64 + pc);
#pragma unroll
      for (int ni = 0; ni < 4; ++ni)
        bfr[ni] = *(const bf16x8*)(Bs + (wc * 64 + ni * 16 + rl) * 64 + pc);
#pragma unroll
      for (int mi = 0; mi < 4; ++mi)
#pragma unroll
        for (int ni = 0; ni < 4; ++ni)
          acc[mi][ni] = __builtin_amdgcn_mfma_f32_16x16x32_bf16(
              af[mi], bfr[ni], acc[mi][ni], 0, 0, 0);
    }
  };

  loadA(0);
  for (int kt = 0; kt < 4; ++kt) {
    writeA();
    stageB(kt);
    if (kt + 1 < 4) loadA(kt + 1);
    __syncthreads();
    compute();
    __syncthreads();
  }

  const int rl = lane & 15, rg = lane >> 4;
  const float SCALE = 0.17677669529663689f;  // 32^-0.5
#pragma unroll
  for (int mi = 0; mi < 4; ++mi) {
#pragma unroll
    for (int ni = 0; ni < 4; ++ni) {
      const int col = col0 + wc * 64 + ni * 16 + rl;
      const float bcol = bias[col];
      const int i0 = wr * 64 + mi * 16 + rg * 4;
      const int hd = i0 & 31, hil = i0 >> 5;
      const int wi = (hp * 4 + hil) * 256 + col;
      BF4 pk;
#pragma unroll
      for (int r = 0; r < 4; ++r)
        pk.v[r] = f2b((acc[mi][ni][r] + bcol) * SCALE);
      *(BF4*)(Qa + ((((size_t)bb * 4096 + wi) * 8 + nh) * 128 + qi * 32 + hd)) = pk;
    }
  }
}

// ---------------------------------------------------------------------------
// Windowed attention v3: no LDS, no QK shuffles. 16-lane group per (w,nh),
// lane = qi*4+kj. q from Qa (hd-contig, pre-scaled), k/v from KV512
// (row l_x = kj*4096+wi; cols [0:256)=K, [256:512)=V; hd-contig 64B runs).
// ---------------------------------------------------------------------------
__global__ void __launch_bounds__(256) attn_kernel(
    const BF* __restrict__ Qa, const BF* __restrict__ KV,
    const float* __restrict__ biasb, BF* __restrict__ O) {
  const int t = threadIdx.x;
  const int g = t >> 4, l16 = t & 15;
  const int qi = l16 >> 2, kj = l16 & 3;
  const int w = (blockIdx.x << 1) | (g >> 3);
  const int nh = g & 7;
  const int b = w >> 12, wi = w & 4095;

  const uint4* qp = (const uint4*)(Qa + ((((size_t)b * 4096 + wi) * 8 + nh) * 128 + qi * 32));
  uint4 qv[4] = {qp[0], qp[1], qp[2], qp[3]};
  const uint4* kp = (const uint4*)(KV + ((size_t)b * 16384 + kj * 4096 + wi) * 512 + nh * 32);
  uint4 kv[4] = {kp[0], kp[1], kp[2], kp[3]};
  const float bias_l = biasb[(size_t)w * 128 + nh * 16 + l16];
  const BF* vbase = KV + (size_t)b * 16384 * 512 + 256 + nh * 32 + kj * 8;
  uint4 vv[4];
#pragma unroll
  for (int d = 0; d < 4; ++d)
    vv[d] = *(const uint4*)(vbase + ((size_t)((kj ^ d) * 4096 + wi)) * 512);

  float accs[4] = {0.f, 0.f, 0.f, 0.f};
#pragma unroll
  for (int j = 0; j < 4; ++j) {
#pragma unroll
    for (int e = 0; e < 4; ++e) {
      unsigned qe = ((const unsigned*)&qv[j])[e];
      unsigned ke = ((const unsigned*)&kv[j])[e];
      float ql = __uint_as_float(qe << 16);
      float qh = __uint_as_float(qe & 0xffff0000u);
      float kl = __uint_as_float(ke << 16);
      float kh = __uint_as_float(ke & 0xffff0000u);
      accs[e] = fmaf(ql, kl, accs[e]);
      accs[e] = fmaf(qh, kh, accs[e]);
    }
  }
  const float score = accs[0] + accs[1] + accs[2] + accs[3] + bias_l;

  float mx = fmaxf(score, __shfl_xor(score, 1));
  mx = fmaxf(mx, __shfl_xor(mx, 2));
  float e = __expf(score - mx);
  float sm = e + __shfl_xor(e, 1);
  sm += __shfl_xor(sm, 2);
  float p = e / sm;
  float pd[4];
  pd[0] = p;
  pd[1] = __shfl_xor(p, 1);
  pd[2] = __shfl_xor(p, 2);
  pd[3] = __shfl_xor(pd[1], 2);

  float o8[8] = {0.f, 0.f, 0.f, 0.f, 0.f, 0.f, 0.f, 0.f};
#pragma unroll
  for (int d = 0; d < 4; ++d) {
#pragma unroll
    for (int e2 = 0; e2 < 4; ++e2) {
      unsigned ve = ((const unsigned*)&vv[d])[e2];
      o8[e2 * 2 + 0] = fmaf(pd[d], __uint_as_float(ve << 16), o8[e2 * 2 + 0]);
      o8[e2 * 2 + 1] = fmaf(pd[d], __uint_as_float(ve & 0xffff0000u), o8[e2 * 2 + 1]);
    }
  }
  BF8 ob;
#pragma unroll
  for (int h = 0; h < 8; ++h) ob.v[h] = f2b(o8[h]);
  *(BF8*)(O + ((size_t)b * 16384 + qi * 4096 + wi) * 256 + nh * 32 + kj * 8) = ob;
}

// ---------------------------------------------------------------------------
// LayerNorm over C=256: one 64-lane wave per row, 4 bf16 per lane.
// ---------------------------------------------------------------------------
__global__ void __launch_bounds__(256) ln_kernel(
    const BF* __restrict__ S1, const float* __restrict__ g,
    const float* __restrict__ be, BF* __restrict__ Nout) {
  const int wave = threadIdx.x >> 6, lane = threadIdx.x & 63;
  const size_t row = (size_t)blockIdx.x * 4 + wave;
  BF4 d = *(const BF4*)(S1 + row * 256 + lane * 4);
  float x[4] = {b2f(d.v[0]), b2f(d.v[1]), b2f(d.v[2]), b2f(d.v[3])};
  float s = x[0] + x[1] + x[2] + x[3];
  float sq = x[0] * x[0] + x[1] * x[1] + x[2] * x[2] + x[3] * x[3];
#pragma unroll
  for (int m = 1; m <= 32; m <<= 1) {
    s += __shfl_xor(s, m);
    sq += __shfl_xor(sq, m);
  }
  const float mean = s * 0.00390625f;
  const float var = sq * 0.00390625f - mean * mean;
  const float rstd = 1.0f / sqrtf(var + 1e-5f);
  BF4 o;
#pragma unroll
  for (int jj = 0; jj < 4; ++jj) {
    float nv = (x[jj] - mean) * rstd * g[lane * 4 + jj] + be[lane * 4 + jj];
    o.v[jj] = f2b(nv);
  }
  *(BF4*)(Nout + row * 256 + lane * 4) = o;
}

// ---------------------------------------------------------------------------
// ws layout (bytes):
//   [0,          8388608)   rel-bias f32 (nW*128)
//   [8388608,    41943040)  Qa bf16 [b][wi][nh][qi][hd] -> LN out after attn
//   [41943040,  109051904)  KV512 bf16 (65536 x 512; K|V halves) -> H2 after
//   [109051904, 142606336)  S1 bf16
//   [142606336, ~144.2MB)   bf16 weights Wq,Wo, Wkv(stacked), mw1, mw2; bkv f32
// d_out doubles as bf16 attn-output staging (consumed by Wo-GEMM, then
// overwritten with final f32 by MLP2).
// ---------------------------------------------------------------------------
extern "C" void kernel_launch(void* const* d_in, const int* in_sizes, int n_in,
                              void* d_out, int out_size, void* d_ws, size_t ws_size,
                              hipStream_t stream) {
  const float* s     = (const float*)d_in[0];
  const float* x     = (const float*)d_in[1];
  const float* s_pos = (const float*)d_in[2];
  const float* x_pos = (const float*)d_in[3];
  const float* Wq = (const float*)d_in[4];  const float* bq = (const float*)d_in[5];
  const float* Wk = (const float*)d_in[6];  const float* bk = (const float*)d_in[7];
  const float* Wv = (const float*)d_in[8];  const float* bv = (const float*)d_in[9];
  const float* Wo = (const float*)d_in[10]; const float* bo = (const float*)d_in[11];
  const float* pw1 = (const float*)d_in[12]; const float* pb1 = (const float*)d_in[13];
  const float* bn_g = (const float*)d_in[14]; const float* bn_b = (const float*)d_in[15];
  const float* bn_m = (const float*)d_in[16]; const float* bn_v = (const float*)d_in[17];
  const float* pw2 = (const float*)d_in[18]; const float* pb2 = (const float*)d_in[19];
  const float* ln_g = (const float*)d_in[20]; const float* ln_b = (const float*)d_in[21];
  const float* mw1 = (const float*)d_in[22]; const float* mb1 = (const float*)d_in[23];
  const float* mw2 = (const float*)d_in[24]; const float* mb2 = (const float*)d_in[25];

  char* ws = (char*)d_ws;
  float* biasb = (float*)ws;
  BF* Qa   = (BF*)(ws + 8388608);
  BF* KVw  = (BF*)(ws + 41943040);
  BF* S1   = (BF*)(ws + 109051904);
  BF* Wq_bf  = (BF*)(ws + 142606336);
  BF* Wo_bf  = (BF*)(ws + 142737408);
  BF* Wkv_bf = (BF*)(ws + 142868480);
  BF* mw1_bf = (BF*)(ws + 143130624);
  BF* mw2_bf = (BF*)(ws + 143654912);
  float* bkv = (float*)(ws + 144179200);
  BF* Nw = Qa;            // LN output reuses Qa region (free after attn)
  BF* H2 = KVw;           // MLP hidden reuses KV region (free after attn)
  BF* ObBF = (BF*)d_out;  // attn output staged bf16 inside d_out
  float* Of = (float*)d_out;

  cvt_kernel<<<64, 256, 0, stream>>>(Wq, Wq_bf, 16384);
  cvt_kernel<<<64, 256, 0, stream>>>(Wo, Wo_bf, 16384);
  cvt_kernel<<<64, 256, 0, stream>>>(Wk, Wkv_bf, 16384);
  cvt_kernel<<<64, 256, 0, stream>>>(Wv, Wkv_bf + 65536, 16384);
  cvt_kernel<<<256, 256, 0, stream>>>(mw1, mw1_bf, 65536);
  cvt_kernel<<<256, 256, 0, stream>>>(mw2, mw2_bf, 65536);
  bkv_kernel<<<2, 256, 0, stream>>>(bk, bv, bkv);
  bias_kernel<<<1024, 256, 0, stream>>>(s_pos, x_pos, pw1, pb1, bn_g, bn_b,
                                        bn_m, bn_v, pw2, pb2, biasb);

  gemm_q<<<1024, 256, 0, stream>>>(s, Wq_bf, bq, Qa);
  gemm_tn<EPI_NONE, float, float, BF><<<2048, 256, 0, stream>>>(
      x, Wkv_bf, bkv, nullptr, KVw, 65536, 512, 256);
  attn_kernel<<<8192, 256, 0, stream>>>(Qa, KVw, biasb, ObBF);
  gemm_tn<EPI_RES, BF, float, BF><<<1024, 256, 0, stream>>>(
      ObBF, Wo_bf, bo, s, S1, 65536, 256, 256);
  ln_kernel<<<16384, 256, 0, stream>>>(S1, ln_g, ln_b, Nw);
  for (int h = 0; h < 2; ++h) {
    const size_t ro = (size_t)h * 32768;
    gemm_tn<EPI_GELU, BF, float, BF><<<2048, 256, 0, stream>>>(
        Nw + ro * 256, mw1_bf, mb1, nullptr, H2, 32768, 1024, 256);
    gemm_tn<EPI_RES, BF, BF, float><<<512, 256, 0, stream>>>(
        H2, mw2_bf, mb2, S1 + ro * 256, Of + ro * 256, 32768, 256, 1024);
  }
}